// Round 4
// baseline (538.964 us; speedup 1.0000x reference)
//
#include <hip/hip_runtime.h>
#include <hip/hip_bf16.h>

#define FEAT 128
#define NRELS 8
#define SCAN_CHUNK 256

typedef __bf16 bf16_t;
typedef __bf16 bf16x2_t __attribute__((ext_vector_type(2)));
typedef __bf16 bf16x8_t __attribute__((ext_vector_type(8)));
typedef float f32x4 __attribute__((ext_vector_type(4)));

struct __align__(8) PackedEdge { int row; float scale; };  // row = src*8 + rel

static inline size_t align256(size_t x) { return (x + 255) & ~(size_t)255; }

// ---------------------------------------------------------------------------
// W [r][d][f] fp32 -> Wt [f][r*128+d] bf16  (A-operand: m=fout rows, k=r*128+d
// contiguous per row -> 16B vector loads of 8 k-elements).
__global__ void k_convert_w(const float* __restrict__ w, bf16_t* __restrict__ wt) {
    int i = blockIdx.x * blockDim.x + threadIdx.x;
    if (i >= NRELS * FEAT * FEAT) return;
    int r = i >> 14;
    int rem = i & 16383;
    int d = rem >> 7;
    int f = rem & 127;
    wt[(size_t)f * (NRELS * FEAT) + r * FEAT + d] = (bf16_t)w[i];
}

// ---------------------------------------------------------------------------
// Gate: sg[n][r] = sigmoid(sum_d h[n][d]*gw[r][d]); fp32. One wave per node.
__global__ void k_gate(const float* __restrict__ h, const float* __restrict__ gw,
                       float* __restrict__ sg, int ncount) {
    int wv = (int)((blockIdx.x * blockDim.x + threadIdx.x) >> 6);
    int lane = threadIdx.x & 63;
    if (wv >= ncount) return;
    float2 hv = *reinterpret_cast<const float2*>(h + (size_t)wv * FEAT + lane * 2);
    float res[NRELS];
#pragma unroll
    for (int r = 0; r < NRELS; ++r) {
        float2 wvv = *reinterpret_cast<const float2*>(gw + r * FEAT + lane * 2);
        float s = hv.x * wvv.x + hv.y * wvv.y;
#pragma unroll
        for (int off = 32; off; off >>= 1) s += __shfl_xor(s, off, 64);
        res[r] = s;
    }
    if (lane == 0) {
#pragma unroll
        for (int r = 0; r < NRELS; ++r)
            sg[(size_t)wv * NRELS + r] = 1.0f / (1.0f + __expf(-res[r]));
    }
}

// ---------------------------------------------------------------------------
// CSR build over dst
__global__ void k_degree(const int* __restrict__ dstv, int* __restrict__ deg, int nedges) {
    int e = blockIdx.x * blockDim.x + threadIdx.x;
    if (e >= nedges) return;
    atomicAdd(&deg[dstv[e]], 1);
}

__global__ __launch_bounds__(256) void k_scan_block(const int* __restrict__ in,
                                                    int* __restrict__ outv,
                                                    int* __restrict__ bsum, int n) {
    __shared__ int sm[256];
    int t = threadIdx.x;
    int idx = blockIdx.x * SCAN_CHUNK + t;
    int v = (idx < n) ? in[idx] : 0;
    sm[t] = v;
    __syncthreads();
    for (int off = 1; off < 256; off <<= 1) {
        int x = (t >= off) ? sm[t - off] : 0;
        __syncthreads();
        sm[t] += x;
        __syncthreads();
    }
    if (idx < n) outv[idx] = sm[t] - v;
    if (t == 255) bsum[blockIdx.x] = sm[255];
}

__global__ __launch_bounds__(1024) void k_scan_tops(int* __restrict__ bsum, int nb,
                                                    int* __restrict__ rowptr_end) {
    __shared__ int sm[1024];
    int t = threadIdx.x;
    if (nb <= 1024) {
        int v = (t < nb) ? bsum[t] : 0;
        sm[t] = v;
        __syncthreads();
        for (int off = 1; off < 1024; off <<= 1) {
            int x = (t >= off) ? sm[t - off] : 0;
            __syncthreads();
            sm[t] += x;
            __syncthreads();
        }
        if (t < nb) bsum[t] = sm[t] - v;
        if (t == 1023) *rowptr_end = sm[1023];
    } else if (t == 0) {
        int run = 0;
        for (int b = 0; b < nb; ++b) { int v = bsum[b]; bsum[b] = run; run += v; }
        *rowptr_end = run;
    }
}

__global__ void k_scan_add(int* __restrict__ rowptr, const int* __restrict__ bsum, int n) {
    int i = blockIdx.x * blockDim.x + threadIdx.x;
    if (i >= n) return;
    rowptr[i] += bsum[i >> 8];
}

__global__ void k_fill(const int* __restrict__ src, const int* __restrict__ dstv,
                       const int* __restrict__ rel, const float* __restrict__ nrm,
                       const float* __restrict__ sg, const int* __restrict__ rowptr,
                       int* __restrict__ cursor, PackedEdge* __restrict__ packed,
                       int nedges) {
    int e = blockIdx.x * blockDim.x + threadIdx.x;
    if (e >= nedges) return;
    int d = dstv[e];
    int s = src[e];
    int r = rel[e];
    int pos = rowptr[d] + atomicAdd(&cursor[d], 1);
    PackedEdge p;
    p.row = s * NRELS + r;
    p.scale = nrm[e] * sg[(size_t)s * NRELS + r];
    packed[pos] = p;
}

// ---------------------------------------------------------------------------
// Fused aggregate + transform.
// Phase A: wave wv aggregates dst nodes [tile*32+wv*8, +8): walks their merged
//   CSR edge range with a depth-3 load pipeline (2 h-rows in flight), lane l
//   accumulates feats {2l,2l+1} x 8 rels in fp32 regs (rel-select via cndmask),
//   flushes bf16 to LDS agg tile [32 nodes][K=1024], 16B-chunk XOR-swizzled.
// Phase B: GEMM out[node][fout] = sum_k agg[node][k] * Wt[fout][k], K=1024,
//   M=128 (fout; wave covers 32), N=32 (nodes). Fused ReLU, float4 stores.
__global__ __launch_bounds__(256, 2) void k_fused(const float* __restrict__ h,
                                                  const bf16_t* __restrict__ wt,
                                                  const PackedEdge* __restrict__ packed,
                                                  const int* __restrict__ rowptr,
                                                  float* __restrict__ out, int nnodes) {
    __shared__ bf16_t smem[32 * 1024];    // 64 KiB -> 2 blocks/CU
    const int tile = blockIdx.x;
    const int wv = threadIdx.x >> 6;
    const int lane = threadIdx.x & 63;

    // ---------------- Phase A ----------------
    const int n0 = tile * 32 + wv * 8;
    float ax[NRELS], ay[NRELS];
#pragma unroll
    for (int r = 0; r < NRELS; ++r) { ax[r] = 0.f; ay[r] = 0.f; }

    auto flush = [&](int nn) {
        int ln = nn - tile * 32;
        int sw = ln & 7;
        bf16_t* rowp = smem + ln * 1024;
#pragma unroll
        for (int r = 0; r < NRELS; ++r) {
            int chunk = r * 16 + (lane >> 2);                 // 16B chunk 0..127
            int off = ((chunk ^ sw) << 3) + ((lane & 3) << 1);
            bf16x2_t v;
            v.x = (bf16_t)ax[r];
            v.y = (bf16_t)ay[r];
            *reinterpret_cast<bf16x2_t*>(rowp + off) = v;
            ax[r] = 0.f;
            ay[r] = 0.f;
        }
    };

    int c0 = n0 < nnodes ? n0 : nnodes;
    int c8 = (n0 + 8) < nnodes ? (n0 + 8) : nnodes;
    int b0 = rowptr[c0];
    int b8 = rowptr[c8];
    int n = n0;
    int nextb = rowptr[(n + 1) < nnodes ? (n + 1) : nnodes];

    int j = b0;
    PackedEdge p0, p1;
    float2 h0v, h1v;
    p0.row = 0; p0.scale = 0.f; p1 = p0;
    h0v = make_float2(0.f, 0.f); h1v = h0v;
    if (j < b8) {
        p0 = packed[j];
        h0v = *reinterpret_cast<const float2*>(h + (size_t)(p0.row >> 3) * FEAT + lane * 2);
    }
    if (j + 1 < b8) {
        p1 = packed[j + 1];
        h1v = *reinterpret_cast<const float2*>(h + (size_t)(p1.row >> 3) * FEAT + lane * 2);
    }
#pragma unroll 1
    for (; j < b8; ++j) {
        PackedEdge p2; float2 h2v;
        p2.row = 0; p2.scale = 0.f; h2v = make_float2(0.f, 0.f);
        if (j + 2 < b8) {
            p2 = packed[j + 2];
            h2v = *reinterpret_cast<const float2*>(h + (size_t)(p2.row >> 3) * FEAT + lane * 2);
        }
        while (j >= nextb) {                     // node boundary: flush, advance
            flush(n);
            ++n;
            nextb = rowptr[(n + 1) < nnodes ? (n + 1) : nnodes];
        }
        float s = p0.scale;
        int rl = p0.row & 7;
#pragma unroll
        for (int r = 0; r < NRELS; ++r) {
            float sr = (rl == r) ? s : 0.f;
            ax[r] += h0v.x * sr;
            ay[r] += h0v.y * sr;
        }
        p0 = p1; h0v = h1v;
        p1 = p2; h1v = h2v;
    }
    while (n < n0 + 8) { flush(n); ++n; }

    __syncthreads();

    // ---------------- Phase B ----------------
    const int l15 = lane & 15;
    const int lhi = lane >> 4;
    f32x4 acc[2][2];
#pragma unroll
    for (int tm = 0; tm < 2; ++tm)
#pragma unroll
        for (int tn = 0; tn < 2; ++tn)
            acc[tm][tn] = (f32x4){0.f, 0.f, 0.f, 0.f};

    const bf16_t* wbase = wt + (size_t)(wv * 32) * (NRELS * FEAT);
#pragma unroll 2
    for (int ks = 0; ks < 32; ++ks) {
        bf16x8_t af[2], bfv[2];
#pragma unroll
        for (int tm = 0; tm < 2; ++tm)
            af[tm] = *reinterpret_cast<const bf16x8_t*>(
                wbase + (size_t)(tm * 16 + l15) * (NRELS * FEAT) + ks * 32 + lhi * 8);
#pragma unroll
        for (int tn = 0; tn < 2; ++tn) {
            int ln = tn * 16 + l15;
            int chunk = ks * 4 + lhi;
            bfv[tn] = *reinterpret_cast<const bf16x8_t*>(
                smem + ln * 1024 + ((chunk ^ (ln & 7)) << 3));
        }
#pragma unroll
        for (int tm = 0; tm < 2; ++tm)
#pragma unroll
            for (int tn = 0; tn < 2; ++tn)
                acc[tm][tn] = __builtin_amdgcn_mfma_f32_16x16x32_bf16(
                    af[tm], bfv[tn], acc[tm][tn], 0, 0, 0);
    }

    // Store: node = tile*32 + tn*16 + l15; fout = wv*32 + tm*16 + lhi*4 + i
#pragma unroll
    for (int tn = 0; tn < 2; ++tn) {
        int node = tile * 32 + tn * 16 + l15;
        if (node < nnodes) {
#pragma unroll
            for (int tm = 0; tm < 2; ++tm) {
                int f0 = wv * 32 + tm * 16 + lhi * 4;
                float4 o;
                o.x = fmaxf(acc[tm][tn][0], 0.f);
                o.y = fmaxf(acc[tm][tn][1], 0.f);
                o.z = fmaxf(acc[tm][tn][2], 0.f);
                o.w = fmaxf(acc[tm][tn][3], 0.f);
                *reinterpret_cast<float4*>(out + (size_t)node * FEAT + f0) = o;
            }
        }
    }
}

// ---------------------------------------------------------------------------
extern "C" void kernel_launch(void* const* d_in, const int* in_sizes, int n_in,
                              void* d_out, int out_size, void* d_ws, size_t ws_size,
                              hipStream_t stream) {
    const float* h = (const float*)d_in[0];
    const float* w = (const float*)d_in[1];
    const float* gw = (const float*)d_in[2];
    const float* nrm = (const float*)d_in[3];
    const int* src = (const int*)d_in[4];
    const int* dst = (const int*)d_in[5];
    const int* rel = (const int*)d_in[6];
    float* out = (float*)d_out;

    const int N = in_sizes[0] / FEAT;
    const int E = in_sizes[4];
    const int nb = (N + SCAN_CHUNK - 1) / SCAN_CHUNK;

    char* ws = (char*)d_ws;
    size_t off = 0;
    bf16_t* wt = (bf16_t*)(ws + off);
    off += align256((size_t)NRELS * FEAT * FEAT * sizeof(bf16_t));   // 256 KiB
    float* sg = (float*)(ws + off);
    off += align256((size_t)N * NRELS * sizeof(float));              // 3.2 MB
    int* deg = (int*)(ws + off);
    off += align256((size_t)N * sizeof(int));                        // 0.4 MB
    int* rowptr = (int*)(ws + off);
    off += align256((size_t)(N + 1) * sizeof(int));                  // 0.4 MB
    int* bsum = (int*)(ws + off);
    off += align256((size_t)nb * sizeof(int));
    PackedEdge* packed = (PackedEdge*)(ws + off);
    off += align256((size_t)E * sizeof(PackedEdge));                 // 4.8 MB

    k_convert_w<<<(NRELS * FEAT * FEAT + 255) / 256, 256, 0, stream>>>(w, wt);
    k_gate<<<(N + 3) / 4, 256, 0, stream>>>(h, gw, sg, N);
    hipMemsetAsync(deg, 0, (size_t)N * sizeof(int), stream);
    k_degree<<<(E + 255) / 256, 256, 0, stream>>>(dst, deg, E);
    k_scan_block<<<nb, 256, 0, stream>>>(deg, rowptr, bsum, N);
    k_scan_tops<<<1, 1024, 0, stream>>>(bsum, nb, rowptr + N);
    k_scan_add<<<(N + 255) / 256, 256, 0, stream>>>(rowptr, bsum, N);
    hipMemsetAsync(deg, 0, (size_t)N * sizeof(int), stream);         // reuse as cursor
    k_fill<<<(E + 255) / 256, 256, 0, stream>>>(src, dst, rel, nrm, sg, rowptr, deg, packed, E);
    k_fused<<<(N + 31) / 32, 256, 0, stream>>>(h, wt, packed, rowptr, out, N);
}

// Round 5
// 469.905 us; speedup vs baseline: 1.1470x; 1.1470x over previous
//
#include <hip/hip_runtime.h>
#include <hip/hip_bf16.h>

#define FEAT 128
#define NRELS 8
#define SCAN_CHUNK 256

typedef __bf16 bf16_t;
typedef __bf16 bf16x2_t __attribute__((ext_vector_type(2)));
typedef __bf16 bf16x8_t __attribute__((ext_vector_type(8)));
typedef float f32x4 __attribute__((ext_vector_type(4)));

struct __align__(8) PackedEdge { int row; float scale; };  // row = src*8 + rel

static inline size_t align256(size_t x) { return (x + 255) & ~(size_t)255; }

// ---------------------------------------------------------------------------
// W [r][d][f] fp32 -> Wt [f][r*128+d] bf16  (A-operand: m=fout rows, k=r*128+d
// contiguous per row -> 16B vector loads of 8 k-elements).
__global__ void k_convert_w(const float* __restrict__ w, bf16_t* __restrict__ wt) {
    int i = blockIdx.x * blockDim.x + threadIdx.x;
    if (i >= NRELS * FEAT * FEAT) return;
    int r = i >> 14;
    int rem = i & 16383;
    int d = rem >> 7;
    int f = rem & 127;
    wt[(size_t)f * (NRELS * FEAT) + r * FEAT + d] = (bf16_t)w[i];
}

// ---------------------------------------------------------------------------
// Gate: sg[n][r] = sigmoid(sum_d h[n][d]*gw[r][d]); fp32. One wave per node.
__global__ void k_gate(const float* __restrict__ h, const float* __restrict__ gw,
                       float* __restrict__ sg, int ncount) {
    int wv = (int)((blockIdx.x * blockDim.x + threadIdx.x) >> 6);
    int lane = threadIdx.x & 63;
    if (wv >= ncount) return;
    float2 hv = *reinterpret_cast<const float2*>(h + (size_t)wv * FEAT + lane * 2);
    float res[NRELS];
#pragma unroll
    for (int r = 0; r < NRELS; ++r) {
        float2 wvv = *reinterpret_cast<const float2*>(gw + r * FEAT + lane * 2);
        float s = hv.x * wvv.x + hv.y * wvv.y;
#pragma unroll
        for (int off = 32; off; off >>= 1) s += __shfl_xor(s, off, 64);
        res[r] = s;
    }
    if (lane == 0) {
#pragma unroll
        for (int r = 0; r < NRELS; ++r)
            sg[(size_t)wv * NRELS + r] = 1.0f / (1.0f + __expf(-res[r]));
    }
}

// ---------------------------------------------------------------------------
// CSR build over dst
__global__ void k_degree(const int* __restrict__ dstv, int* __restrict__ deg, int nedges) {
    int e = blockIdx.x * blockDim.x + threadIdx.x;
    if (e >= nedges) return;
    atomicAdd(&deg[dstv[e]], 1);
}

__global__ __launch_bounds__(256) void k_scan_block(const int* __restrict__ in,
                                                    int* __restrict__ outv,
                                                    int* __restrict__ bsum, int n) {
    __shared__ int sm[256];
    int t = threadIdx.x;
    int idx = blockIdx.x * SCAN_CHUNK + t;
    int v = (idx < n) ? in[idx] : 0;
    sm[t] = v;
    __syncthreads();
    for (int off = 1; off < 256; off <<= 1) {
        int x = (t >= off) ? sm[t - off] : 0;
        __syncthreads();
        sm[t] += x;
        __syncthreads();
    }
    if (idx < n) outv[idx] = sm[t] - v;
    if (t == 255) bsum[blockIdx.x] = sm[255];
}

__global__ __launch_bounds__(1024) void k_scan_tops(int* __restrict__ bsum, int nb,
                                                    int* __restrict__ rowptr_end) {
    __shared__ int sm[1024];
    int t = threadIdx.x;
    if (nb <= 1024) {
        int v = (t < nb) ? bsum[t] : 0;
        sm[t] = v;
        __syncthreads();
        for (int off = 1; off < 1024; off <<= 1) {
            int x = (t >= off) ? sm[t - off] : 0;
            __syncthreads();
            sm[t] += x;
            __syncthreads();
        }
        if (t < nb) bsum[t] = sm[t] - v;
        if (t == 1023) *rowptr_end = sm[1023];
    } else if (t == 0) {
        int run = 0;
        for (int b = 0; b < nb; ++b) { int v = bsum[b]; bsum[b] = run; run += v; }
        *rowptr_end = run;
    }
}

__global__ void k_scan_add(int* __restrict__ rowptr, const int* __restrict__ bsum, int n) {
    int i = blockIdx.x * blockDim.x + threadIdx.x;
    if (i >= n) return;
    rowptr[i] += bsum[i >> 8];
}

__global__ void k_fill(const int* __restrict__ src, const int* __restrict__ dstv,
                       const int* __restrict__ rel, const float* __restrict__ nrm,
                       const float* __restrict__ sg, const int* __restrict__ rowptr,
                       int* __restrict__ cursor, PackedEdge* __restrict__ packed,
                       int nedges) {
    int e = blockIdx.x * blockDim.x + threadIdx.x;
    if (e >= nedges) return;
    int d = dstv[e];
    int s = src[e];
    int r = rel[e];
    int pos = rowptr[d] + atomicAdd(&cursor[d], 1);
    PackedEdge p;
    p.row = s * NRELS + r;
    p.scale = nrm[e] * sg[(size_t)s * NRELS + r];
    packed[pos] = p;
}

// ---------------------------------------------------------------------------
// Fused aggregate + transform.
// Phase A (rewritten for MLP): wave wv owns dst nodes [n0, n0+8). rowptr[n0..n0+8]
//   is preloaded into registers (lane-held + shfl) -- the boundary walk is pure
//   register compares. The merged edge range [b0,b8) is processed in chunks of 8:
//   8 independent h-row loads in flight per chunk, next chunk's packed records
//   prefetched during accumulation (2-stage pipeline). Lane l accumulates feats
//   {2l,2l+1} x 8 rels in fp32, flushes bf16 to the swizzled LDS agg tile.
// Phase B: GEMM out[node][fout] = sum_k agg[node][k] * Wt[fout][k], K=1024,
//   fused ReLU, float4 stores.
__global__ __launch_bounds__(256, 2) void k_fused(const float* __restrict__ h,
                                                  const bf16_t* __restrict__ wt,
                                                  const PackedEdge* __restrict__ packed,
                                                  const int* __restrict__ rowptr,
                                                  float* __restrict__ out, int nnodes) {
    __shared__ bf16_t smem[32 * 1024];    // 64 KiB -> 2 blocks/CU
    const int tile = blockIdx.x;
    const int wv = threadIdx.x >> 6;
    const int lane = threadIdx.x & 63;

    // ---------------- Phase A ----------------
    const int n0 = tile * 32 + wv * 8;
    float ax[NRELS], ay[NRELS];
#pragma unroll
    for (int r = 0; r < NRELS; ++r) { ax[r] = 0.f; ay[r] = 0.f; }

    auto flush = [&](int cur) {
        int ln = wv * 8 + cur;
        int sw = ln & 7;
        bf16_t* rowp = smem + ln * 1024;
#pragma unroll
        for (int r = 0; r < NRELS; ++r) {
            int chunk = r * 16 + (lane >> 2);                 // 16B chunk 0..127
            int off = ((chunk ^ sw) << 3) + ((lane & 3) << 1);
            bf16x2_t v;
            v.x = (bf16_t)ax[r];
            v.y = (bf16_t)ay[r];
            *reinterpret_cast<bf16x2_t*>(rowp + off) = v;
            ax[r] = 0.f;
            ay[r] = 0.f;
        }
    };

    // rowptr[n0 .. n0+8] -> registers (lane-held, shfl-broadcast)
    int rp_lane = 0;
    if (lane <= 8) {
        int idx = n0 + lane;
        rp_lane = rowptr[idx < nnodes ? idx : nnodes];
    }
    const int b0 = __shfl(rp_lane, 0);
    const int b8 = __shfl(rp_lane, 8);
    int cur = 0;
    int nb_cur = __shfl(rp_lane, 1);

    PackedEdge rec[8], rec2[8];
    int j0 = b0;
    int cnt = b8 - j0; cnt = cnt > 8 ? 8 : cnt;
#pragma unroll
    for (int k = 0; k < 8; ++k)
        if (k < cnt) rec[k] = packed[j0 + k];

#pragma unroll 1
    while (j0 < b8) {
        // issue all h loads for current chunk (independent)
        float2 hv[8];
#pragma unroll
        for (int k = 0; k < 8; ++k)
            if (k < cnt)
                hv[k] = *reinterpret_cast<const float2*>(
                    h + (size_t)(rec[k].row >> 3) * FEAT + lane * 2);

        // prefetch next chunk's packed records (independent of current)
        int j1 = j0 + 8;
        int cnt2 = b8 - j1; cnt2 = cnt2 > 8 ? 8 : (cnt2 < 0 ? 0 : cnt2);
#pragma unroll
        for (int k = 0; k < 8; ++k)
            if (k < cnt2) rec2[k] = packed[j1 + k];

        // accumulate current chunk
#pragma unroll
        for (int k = 0; k < 8; ++k) {
            if (k < cnt) {
                int j = j0 + k;
                while (j >= nb_cur) {            // register-only boundary walk
                    flush(cur);
                    ++cur;
                    nb_cur = __shfl(rp_lane, cur + 1);
                }
                float s = rec[k].scale;
                int rl = rec[k].row & 7;
                float hx = hv[k].x, hy = hv[k].y;
#pragma unroll
                for (int r = 0; r < NRELS; ++r) {
                    float sr = (rl == r) ? s : 0.f;
                    ax[r] = fmaf(hx, sr, ax[r]);
                    ay[r] = fmaf(hy, sr, ay[r]);
                }
            }
        }
        j0 = j1;
        cnt = cnt2;
#pragma unroll
        for (int k = 0; k < 8; ++k) rec[k] = rec2[k];
    }
    while (cur < 8) { flush(cur); ++cur; }

    __syncthreads();

    // ---------------- Phase B ----------------
    const int l15 = lane & 15;
    const int lhi = lane >> 4;
    f32x4 acc[2][2];
#pragma unroll
    for (int tm = 0; tm < 2; ++tm)
#pragma unroll
        for (int tn = 0; tn < 2; ++tn)
            acc[tm][tn] = (f32x4){0.f, 0.f, 0.f, 0.f};

    const bf16_t* wbase = wt + (size_t)(wv * 32) * (NRELS * FEAT);
#pragma unroll 2
    for (int ks = 0; ks < 32; ++ks) {
        bf16x8_t af[2], bfv[2];
#pragma unroll
        for (int tm = 0; tm < 2; ++tm)
            af[tm] = *reinterpret_cast<const bf16x8_t*>(
                wbase + (size_t)(tm * 16 + l15) * (NRELS * FEAT) + ks * 32 + lhi * 8);
#pragma unroll
        for (int tn = 0; tn < 2; ++tn) {
            int ln = tn * 16 + l15;
            int chunk = ks * 4 + lhi;
            bfv[tn] = *reinterpret_cast<const bf16x8_t*>(
                smem + ln * 1024 + ((chunk ^ (ln & 7)) << 3));
        }
#pragma unroll
        for (int tm = 0; tm < 2; ++tm)
#pragma unroll
            for (int tn = 0; tn < 2; ++tn)
                acc[tm][tn] = __builtin_amdgcn_mfma_f32_16x16x32_bf16(
                    af[tm], bfv[tn], acc[tm][tn], 0, 0, 0);
    }

    // Store: node = tile*32 + tn*16 + l15; fout = wv*32 + tm*16 + lhi*4 + i
#pragma unroll
    for (int tn = 0; tn < 2; ++tn) {
        int node = tile * 32 + tn * 16 + l15;
        if (node < nnodes) {
#pragma unroll
            for (int tm = 0; tm < 2; ++tm) {
                int f0 = wv * 32 + tm * 16 + lhi * 4;
                float4 o;
                o.x = fmaxf(acc[tm][tn][0], 0.f);
                o.y = fmaxf(acc[tm][tn][1], 0.f);
                o.z = fmaxf(acc[tm][tn][2], 0.f);
                o.w = fmaxf(acc[tm][tn][3], 0.f);
                *reinterpret_cast<float4*>(out + (size_t)node * FEAT + f0) = o;
            }
        }
    }
}

// ---------------------------------------------------------------------------
extern "C" void kernel_launch(void* const* d_in, const int* in_sizes, int n_in,
                              void* d_out, int out_size, void* d_ws, size_t ws_size,
                              hipStream_t stream) {
    const float* h = (const float*)d_in[0];
    const float* w = (const float*)d_in[1];
    const float* gw = (const float*)d_in[2];
    const float* nrm = (const float*)d_in[3];
    const int* src = (const int*)d_in[4];
    const int* dst = (const int*)d_in[5];
    const int* rel = (const int*)d_in[6];
    float* out = (float*)d_out;

    const int N = in_sizes[0] / FEAT;
    const int E = in_sizes[4];
    const int nb = (N + SCAN_CHUNK - 1) / SCAN_CHUNK;

    char* ws = (char*)d_ws;
    size_t off = 0;
    bf16_t* wt = (bf16_t*)(ws + off);
    off += align256((size_t)NRELS * FEAT * FEAT * sizeof(bf16_t));   // 256 KiB
    float* sg = (float*)(ws + off);
    off += align256((size_t)N * NRELS * sizeof(float));              // 3.2 MB
    int* deg = (int*)(ws + off);
    off += align256((size_t)N * sizeof(int));                        // 0.4 MB
    int* rowptr = (int*)(ws + off);
    off += align256((size_t)(N + 1) * sizeof(int));                  // 0.4 MB
    int* bsum = (int*)(ws + off);
    off += align256((size_t)nb * sizeof(int));
    PackedEdge* packed = (PackedEdge*)(ws + off);
    off += align256((size_t)E * sizeof(PackedEdge));                 // 4.8 MB

    k_convert_w<<<(NRELS * FEAT * FEAT + 255) / 256, 256, 0, stream>>>(w, wt);
    k_gate<<<(N + 3) / 4, 256, 0, stream>>>(h, gw, sg, N);
    hipMemsetAsync(deg, 0, (size_t)N * sizeof(int), stream);
    k_degree<<<(E + 255) / 256, 256, 0, stream>>>(dst, deg, E);
    k_scan_block<<<nb, 256, 0, stream>>>(deg, rowptr, bsum, N);
    k_scan_tops<<<1, 1024, 0, stream>>>(bsum, nb, rowptr + N);
    k_scan_add<<<(N + 255) / 256, 256, 0, stream>>>(rowptr, bsum, N);
    hipMemsetAsync(deg, 0, (size_t)N * sizeof(int), stream);         // reuse as cursor
    k_fill<<<(E + 255) / 256, 256, 0, stream>>>(src, dst, rel, nrm, sg, rowptr, deg, packed, E);
    k_fused<<<(N + 31) / 32, 256, 0, stream>>>(h, wt, packed, rowptr, out, N);
}